// Round 1
// baseline (208.457 us; speedup 1.0000x reference)
//
#include <hip/hip_runtime.h>
#include <math.h>

// Problem constants
#define BATCH 256
#define IC    1152   // 32*6*6 input capsule positions
#define DD    8
#define OO    10
#define EE    16
#define CHUNK 18     // ijk positions per block
#define NCHUNK 64    // IC / CHUNK
#define BTILE 64     // batches per block
#define NBT   4      // BATCH / BTILE
#define NT    640    // OO * BTILE threads per block

// pass kernel: recompute u_hat on the fly, compute routing coefficients from
// accumulated V (sum of previous squashed v's; logits b = dot(u_hat, V)),
// accumulate partial s[b,o,e] over this block's ijk chunk.
__global__ __launch_bounds__(NT) void caps_pass_kernel(
    const float* __restrict__ x,       // [256][1152][8]
    const float* __restrict__ W,       // [1152][10][8][16]
    const float* __restrict__ V,       // [256][10][16] accumulated v
    float* __restrict__ s_part,        // [NCHUNK][256][10][16]
    int first)
{
    __shared__ float w_lds[OO * DD * EE];     // 1280
    __shared__ float x_lds[BTILE * 9];        // padded stride 9 -> no bank conflict
    __shared__ float logit_lds[OO * BTILE];   // 640

    const int tid = threadIdx.x;
    const int o   = tid >> 6;        // 0..9 (wave id)
    const int bl  = tid & 63;        // 0..63
    const int b   = blockIdx.y * BTILE + bl;
    const int chunk = blockIdx.x;

    // per-thread copy of V[b,o,:]
    float vreg[EE];
    if (first) {
        #pragma unroll
        for (int e = 0; e < EE; ++e) vreg[e] = 0.f;
    } else {
        const float4* vp = reinterpret_cast<const float4*>(V + ((size_t)b * OO + o) * EE);
        #pragma unroll
        for (int q = 0; q < 4; ++q) {
            float4 t = vp[q];
            vreg[q * 4 + 0] = t.x; vreg[q * 4 + 1] = t.y;
            vreg[q * 4 + 2] = t.z; vreg[q * 4 + 3] = t.w;
        }
    }

    float sacc[EE];
    #pragma unroll
    for (int e = 0; e < EE; ++e) sacc[e] = 0.f;

    for (int it = 0; it < CHUNK; ++it) {
        const int ijk = chunk * CHUNK + it;

        // ---- stage W tile (1280 floats) and x tile (64 x 8 floats) ----
        if (tid < 320) {
            float4 wv = reinterpret_cast<const float4*>(W + (size_t)ijk * (OO * DD * EE))[tid];
            reinterpret_cast<float4*>(w_lds)[tid] = wv;
        } else if (tid < 448) {
            int t2  = tid - 320;        // 0..127
            int b_l = t2 >> 1;          // 0..63
            int q   = t2 & 1;           // 0..1
            const float* xp = x + (size_t)(blockIdx.y * BTILE + b_l) * (IC * DD)
                                + (size_t)ijk * DD + q * 4;
            float4 xv = *reinterpret_cast<const float4*>(xp);
            x_lds[b_l * 9 + q * 4 + 0] = xv.x;
            x_lds[b_l * 9 + q * 4 + 1] = xv.y;
            x_lds[b_l * 9 + q * 4 + 2] = xv.z;
            x_lds[b_l * 9 + q * 4 + 3] = xv.w;
        }
        __syncthreads();

        // ---- u[e] = sum_d x[b,ijk,d] * W[ijk,o,d,e] ----
        float xr[DD];
        #pragma unroll
        for (int d = 0; d < DD; ++d) xr[d] = x_lds[bl * 9 + d];

        float u[EE];
        #pragma unroll
        for (int e = 0; e < EE; ++e) u[e] = 0.f;
        #pragma unroll
        for (int d = 0; d < DD; ++d) {
            const float4* wrow = reinterpret_cast<const float4*>(&w_lds[o * (DD * EE) + d * EE]);
            float xd = xr[d];
            #pragma unroll
            for (int q = 0; q < 4; ++q) {
                float4 wv = wrow[q];
                u[q * 4 + 0] += xd * wv.x;
                u[q * 4 + 1] += xd * wv.y;
                u[q * 4 + 2] += xd * wv.z;
                u[q * 4 + 3] += xd * wv.w;
            }
        }

        // ---- routing coefficient c ----
        float c;
        if (first) {
            c = 0.1f;                  // softmax of all-zero logits over O=10
            __syncthreads();           // protect w_lds/x_lds before next staging
        } else {
            float lg = 0.f;
            #pragma unroll
            for (int e = 0; e < EE; ++e) lg += u[e] * vreg[e];
            logit_lds[o * BTILE + bl] = lg;
            __syncthreads();           // all compute-u reads of w_lds done here too
            float m = -1e30f;
            #pragma unroll
            for (int oo = 0; oo < OO; ++oo) m = fmaxf(m, logit_lds[oo * BTILE + bl]);
            float den = 0.f;
            #pragma unroll
            for (int oo = 0; oo < OO; ++oo) den += __expf(logit_lds[oo * BTILE + bl] - m);
            c = __expf(lg - m) / den;
            // no extra barrier needed: next iter's staging touches only w_lds/x_lds,
            // and logit_lds is rewritten only after the next post-staging barrier.
        }

        #pragma unroll
        for (int e = 0; e < EE; ++e) sacc[e] += c * u[e];
    }

    // ---- write partial s for this chunk ----
    float* sp = s_part + (((size_t)chunk * BATCH + b) * OO + o) * EE;
    #pragma unroll
    for (int q = 0; q < 4; ++q) {
        float4 t;
        t.x = sacc[q * 4 + 0]; t.y = sacc[q * 4 + 1];
        t.z = sacc[q * 4 + 2]; t.w = sacc[q * 4 + 3];
        reinterpret_cast<float4*>(sp)[q] = t;
    }
}

// squash kernel: reduce partial s over chunks, squash, update V (or write out).
__global__ __launch_bounds__(256) void caps_squash_kernel(
    const float* __restrict__ s_part,  // [NCHUNK][256][10][16]
    float* __restrict__ V,             // [256][10][16]
    float* __restrict__ out,           // [256][10][16]
    int accum, int last)
{
    const int g = blockIdx.x * 256 + threadIdx.x;   // < 40960
    float s = 0.f;
    for (int ch = 0; ch < NCHUNK; ++ch)
        s += s_part[(size_t)ch * (BATCH * OO * EE) + g];

    // squared norm over the 16-element e axis (lanes g..g+15 share (b,o))
    float sq = s * s;
    #pragma unroll
    for (int m = 1; m < 16; m <<= 1) sq += __shfl_xor(sq, m, 16);

    float scale = sq / (1.f + sq) / (sqrtf(sq) + 1e-6f);
    float v = scale * s;

    if (last)       out[g] = v;
    else if (accum) V[g]  += v;
    else            V[g]   = v;
}

extern "C" void kernel_launch(void* const* d_in, const int* in_sizes, int n_in,
                              void* d_out, int out_size, void* d_ws, size_t ws_size,
                              hipStream_t stream) {
    const float* x = (const float*)d_in[0];   // [256,32,6,6,8]
    const float* W = (const float*)d_in[1];   // [1,32,6,6,10,8,16]
    float* out = (float*)d_out;               // [256,10,16]

    float* s_part = (float*)d_ws;                                   // NCHUNK*40960 floats
    float* V      = s_part + (size_t)NCHUNK * BATCH * OO * EE;      // 40960 floats

    dim3 grid(NCHUNK, NBT), blk(NT);
    const int sq_blocks = (BATCH * OO * EE) / 256;   // 160

    // iteration 1: b=0 -> c uniform 0.1; v1 -> V
    caps_pass_kernel<<<grid, blk, 0, stream>>>(x, W, V, s_part, 1);
    caps_squash_kernel<<<sq_blocks, 256, 0, stream>>>(s_part, V, out, 0, 0);
    // iteration 2: logits = dot(u_hat, v1); V += v2
    caps_pass_kernel<<<grid, blk, 0, stream>>>(x, W, V, s_part, 0);
    caps_squash_kernel<<<sq_blocks, 256, 0, stream>>>(s_part, V, out, 1, 0);
    // iteration 3 (final): logits = dot(u_hat, v1+v2); output v3
    caps_pass_kernel<<<grid, blk, 0, stream>>>(x, W, V, s_part, 0);
    caps_squash_kernel<<<sq_blocks, 256, 0, stream>>>(s_part, V, out, 0, 1);
}

// Round 2
// 160.276 us; speedup vs baseline: 1.3006x; 1.3006x over previous
//
#include <hip/hip_runtime.h>
#include <math.h>

// Problem constants
#define BATCH 256
#define IC    1152   // 32*6*6 input capsule positions
#define DD    8
#define OO    10
#define EE    16
#define BTILE 64     // batches per block
#define NBT   4      // BATCH / BTILE
#define NT    640    // OO * BTILE threads per block (10 waves)
#define CHUNK 18     // ijk positions per block
#define NCHUNK 64    // IC / CHUNK
#define SJ    3      // ijk per round (one barrier per round)
#define ROUNDS (CHUNK / SJ)

// pass kernel: recompute u_hat on the fly.
//  - W is read via wave-uniform scalar loads (o is constant per wave ->
//    readfirstlane forces s_load; FMA consumes W from SGPRs). No W in LDS.
//  - x is double-buffered in LDS, register-prefetched one round ahead.
//  - routing logits exchanged through LDS once per round (SJ=3 ijk share
//    one barrier; u kept in registers across the barrier).
__global__ __launch_bounds__(NT) void caps_pass_kernel(
    const float* __restrict__ x,       // [256][1152][8]
    const float* __restrict__ W,       // [1152][10][8][16]
    const float* __restrict__ V,       // [256][10][16] accumulated v
    float* __restrict__ s_part,        // [NCHUNK][256][10][16]
    int first)
{
    __shared__ float x_lds[2][SJ][DD][BTILE];   // d-major: conflict-free b32 reads
    __shared__ float logit_lds[2][SJ][NT];

    const int tid = threadIdx.x;
    const int o   = tid >> 6;        // wave id 0..9
    const int bl  = tid & 63;
    const int o_u = __builtin_amdgcn_readfirstlane(o);   // wave-uniform o
    const int b   = blockIdx.y * BTILE + bl;
    const int ijk0 = blockIdx.x * CHUNK;

    // per-thread copy of V[b,o,:]
    float vreg[EE];
    if (first) {
        #pragma unroll
        for (int e = 0; e < EE; ++e) vreg[e] = 0.f;
    } else {
        const float4* vp = reinterpret_cast<const float4*>(V + ((size_t)b * OO + o) * EE);
        #pragma unroll
        for (int q = 0; q < 4; ++q) {
            float4 t = vp[q];
            vreg[q * 4 + 0] = t.x; vreg[q * 4 + 1] = t.y;
            vreg[q * 4 + 2] = t.z; vreg[q * 4 + 3] = t.w;
        }
    }

    float sacc[EE];
    #pragma unroll
    for (int e = 0; e < EE; ++e) sacc[e] = 0.f;

    // x loader mapping: threads 0..383 each fetch one float4 per round
    const bool loader = tid < SJ * BTILE * 2;   // 384
    const int ls = tid >> 7;         // 0..2  (which ijk of the round)
    const int lr = tid & 127;
    const int lb = lr >> 1;          // 0..63 (batch within tile)
    const int lq = lr & 1;           // 0..1  (which half of the 8 d's)
    const float* xbase = x + (size_t)(blockIdx.y * BTILE + lb) * (IC * DD) + lq * 4;

    // prologue: load round 0, write to buffer 0
    float4 xpre = make_float4(0.f, 0.f, 0.f, 0.f);
    if (loader) xpre = *reinterpret_cast<const float4*>(xbase + (size_t)(ijk0 + ls) * DD);
    if (loader) {
        x_lds[0][ls][lq * 4 + 0][lb] = xpre.x;
        x_lds[0][ls][lq * 4 + 1][lb] = xpre.y;
        x_lds[0][ls][lq * 4 + 2][lb] = xpre.z;
        x_lds[0][ls][lq * 4 + 3][lb] = xpre.w;
    }
    __syncthreads();

    int p = 0;
    for (int r = 0; r < ROUNDS; ++r) {
        // C: issue global prefetch for round r+1 (latency hidden by compute)
        if (r + 1 < ROUNDS && loader)
            xpre = *reinterpret_cast<const float4*>(
                xbase + (size_t)(ijk0 + (r + 1) * SJ + ls) * DD);

        // A: compute u for SJ ijks; write logits
        float u[SJ][EE];
        float lgr[SJ];
        #pragma unroll
        for (int s = 0; s < SJ; ++s) {
            const int ijk = ijk0 + r * SJ + s;
            const float* wp = W + (size_t)ijk * (OO * DD * EE) + o_u * (DD * EE);
            float xr[DD];
            #pragma unroll
            for (int d = 0; d < DD; ++d) xr[d] = x_lds[p][s][d][bl];
            #pragma unroll
            for (int e = 0; e < EE; ++e) u[s][e] = 0.f;
            #pragma unroll
            for (int d = 0; d < DD; ++d) {
                #pragma unroll
                for (int e = 0; e < EE; ++e)
                    u[s][e] = fmaf(xr[d], wp[d * EE + e], u[s][e]);  // W from SGPR
            }
            if (!first) {
                float lg = 0.f;
                #pragma unroll
                for (int e = 0; e < EE; ++e) lg += u[s][e] * vreg[e];
                lgr[s] = lg;
                logit_lds[p][s][tid] = lg;
            }
        }

        // B: write prefetched x into the other buffer
        if (r + 1 < ROUNDS && loader) {
            x_lds[p ^ 1][ls][lq * 4 + 0][lb] = xpre.x;
            x_lds[p ^ 1][ls][lq * 4 + 1][lb] = xpre.y;
            x_lds[p ^ 1][ls][lq * 4 + 2][lb] = xpre.z;
            x_lds[p ^ 1][ls][lq * 4 + 3][lb] = xpre.w;
        }

        // D: single barrier per round (covers x swap + logit visibility)
        __syncthreads();

        // E: softmax over o, accumulate s
        if (first) {
            #pragma unroll
            for (int s = 0; s < SJ; ++s)
                #pragma unroll
                for (int e = 0; e < EE; ++e) sacc[e] += 0.1f * u[s][e];
        } else {
            #pragma unroll
            for (int s = 0; s < SJ; ++s) {
                float m = -1e30f;
                #pragma unroll
                for (int oo = 0; oo < OO; ++oo)
                    m = fmaxf(m, logit_lds[p][s][oo * 64 + bl]);
                float den = 0.f;
                #pragma unroll
                for (int oo = 0; oo < OO; ++oo)
                    den += __expf(logit_lds[p][s][oo * 64 + bl] - m);
                float c = __expf(lgr[s] - m) / den;
                #pragma unroll
                for (int e = 0; e < EE; ++e) sacc[e] += c * u[s][e];
            }
        }
        p ^= 1;
    }

    // write partial s for this chunk
    float* sp = s_part + (((size_t)blockIdx.x * BATCH + b) * OO + o) * EE;
    #pragma unroll
    for (int q = 0; q < 4; ++q) {
        float4 t;
        t.x = sacc[q * 4 + 0]; t.y = sacc[q * 4 + 1];
        t.z = sacc[q * 4 + 2]; t.w = sacc[q * 4 + 3];
        reinterpret_cast<float4*>(sp)[q] = t;
    }
}

// squash kernel: reduce partial s over chunks, squash, update V (or write out).
__global__ __launch_bounds__(256) void caps_squash_kernel(
    const float* __restrict__ s_part,  // [NCHUNK][256][10][16]
    float* __restrict__ V,             // [256][10][16]
    float* __restrict__ out,           // [256][10][16]
    int accum, int last)
{
    const int g = blockIdx.x * 256 + threadIdx.x;   // < 40960
    float s = 0.f;
    for (int ch = 0; ch < NCHUNK; ++ch)
        s += s_part[(size_t)ch * (BATCH * OO * EE) + g];

    // squared norm over the 16-element e axis (lanes g..g+15 share (b,o))
    float sq = s * s;
    #pragma unroll
    for (int m = 1; m < 16; m <<= 1) sq += __shfl_xor(sq, m, 16);

    float scale = sq / (1.f + sq) / (sqrtf(sq) + 1e-6f);
    float v = scale * s;

    if (last)       out[g] = v;
    else if (accum) V[g]  += v;
    else            V[g]   = v;
}

extern "C" void kernel_launch(void* const* d_in, const int* in_sizes, int n_in,
                              void* d_out, int out_size, void* d_ws, size_t ws_size,
                              hipStream_t stream) {
    const float* x = (const float*)d_in[0];   // [256,32,6,6,8]
    const float* W = (const float*)d_in[1];   // [1,32,6,6,10,8,16]
    float* out = (float*)d_out;               // [256,10,16]

    float* s_part = (float*)d_ws;                                   // NCHUNK*40960 floats
    float* V      = s_part + (size_t)NCHUNK * BATCH * OO * EE;      // 40960 floats

    dim3 grid(NCHUNK, NBT), blk(NT);
    const int sq_blocks = (BATCH * OO * EE) / 256;   // 160

    // iteration 1: b=0 -> c uniform 0.1; v1 -> V
    caps_pass_kernel<<<grid, blk, 0, stream>>>(x, W, V, s_part, 1);
    caps_squash_kernel<<<sq_blocks, 256, 0, stream>>>(s_part, V, out, 0, 0);
    // iteration 2: logits = dot(u_hat, v1); V += v2
    caps_pass_kernel<<<grid, blk, 0, stream>>>(x, W, V, s_part, 0);
    caps_squash_kernel<<<sq_blocks, 256, 0, stream>>>(s_part, V, out, 1, 0);
    // iteration 3 (final): logits = dot(u_hat, v1+v2); output v3
    caps_pass_kernel<<<grid, blk, 0, stream>>>(x, W, V, s_part, 0);
    caps_squash_kernel<<<sq_blocks, 256, 0, stream>>>(s_part, V, out, 0, 1);
}